// Round 1
// baseline (637.916 us; speedup 1.0000x reference)
//
#include <hip/hip_runtime.h>
#include <cstdint>
#include <cstddef>

typedef __attribute__((ext_vector_type(8))) short short8;   // bf16x8 MFMA fragment
typedef __attribute__((ext_vector_type(4))) float f32x4;    // fp32x4 accumulator

#define C_ 512
#define S_ 4096
#define B_ 4
#define EPS_ 1e-6f
#define SCALE_ 0.04419417382415922f   // 512^-0.5, folded into q

__device__ __forceinline__ ushort f2bf(float f) {
    union { float f; uint32_t u; } v; v.f = f;
    uint32_t r = v.u + 0x7FFFu + ((v.u >> 16) & 1u);
    return (ushort)(r >> 16);
}

// ---------------- weight fp32 -> bf16 ----------------
__global__ void wconv_kernel(const float* __restrict__ wq, const float* __restrict__ wk,
                             const float* __restrict__ wv, const float* __restrict__ wo,
                             ushort* __restrict__ out) {
    int i = blockIdx.x * 256 + threadIdx.x;   // grid covers exactly 262144
    out[i]          = f2bf(wq[i]);
    out[262144 + i] = f2bf(wk[i]);
    out[524288 + i] = f2bf(wv[i]);
    out[786432 + i] = f2bf(wo[i]);
}

// ---------------- GroupNorm stats: one block per (b,g) ----------------
__global__ __launch_bounds__(512) void gn_stats_kernel(const float* __restrict__ x,
                                                       float* __restrict__ stats) {
    int bg = blockIdx.x;                       // b*32+g ; channels contiguous
    const float* xp = x + (size_t)bg * 16 * S_;
    float sum = 0.f, ss = 0.f;
    for (int i = threadIdx.x; i < 16 * S_; i += 512) {
        float v = xp[i];
        sum += v; ss += v * v;
    }
    #pragma unroll
    for (int off = 32; off; off >>= 1) {
        sum += __shfl_down(sum, off);
        ss  += __shfl_down(ss, off);
    }
    __shared__ float r0[8], r1[8];
    int wid = threadIdx.x >> 6;
    if ((threadIdx.x & 63) == 0) { r0[wid] = sum; r1[wid] = ss; }
    __syncthreads();
    if (threadIdx.x == 0) {
        float ts = 0.f, tq = 0.f;
        #pragma unroll
        for (int w = 0; w < 8; w++) { ts += r0[w]; tq += r1[w]; }
        float mean = ts / 65536.f;
        float var  = tq / 65536.f - mean * mean;
        stats[bg * 2]     = mean;
        stats[bg * 2 + 1] = rsqrtf(var + EPS_);
    }
}

// ---------------- GroupNorm apply + transpose to h_t[s][c] bf16 ----------------
// grid (16 schunks, 32 groups, 4 batch), 256 threads
__global__ __launch_bounds__(256) void gn_apply_kernel(const float* __restrict__ x,
        const float* __restrict__ gamma, const float* __restrict__ beta,
        const float* __restrict__ stats, ushort* __restrict__ h_t) {
    int sc = blockIdx.x, g = blockIdx.y, b = blockIdx.z;
    int c0 = g * 16;
    int bg = b * 32 + g;
    float mean = stats[bg * 2], rstd = stats[bg * 2 + 1];
    int t = threadIdx.x;
    __shared__ float tile[16][257];
    const float* xp = x + ((size_t)b * C_ + c0) * S_ + sc * 256;
    {
        int c = t >> 4, s0 = (t & 15) * 4;
        const float* src = xp + (size_t)c * S_;
        #pragma unroll
        for (int j = 0; j < 4; j++) {
            float4 d = *(const float4*)(src + s0 + 64 * j);
            tile[c][s0 + 64 * j + 0] = d.x;
            tile[c][s0 + 64 * j + 1] = d.y;
            tile[c][s0 + 64 * j + 2] = d.z;
            tile[c][s0 + 64 * j + 3] = d.w;
        }
    }
    __syncthreads();
    {
        float vv[16];
        #pragma unroll
        for (int ci = 0; ci < 16; ci++) {
            float a = rstd * gamma[c0 + ci];
            float bb2 = beta[c0 + ci] - mean * a;
            vv[ci] = tile[ci][t] * a + bb2;
        }
        uint4 lo, hi;
        lo.x = (uint32_t)f2bf(vv[0])  | ((uint32_t)f2bf(vv[1])  << 16);
        lo.y = (uint32_t)f2bf(vv[2])  | ((uint32_t)f2bf(vv[3])  << 16);
        lo.z = (uint32_t)f2bf(vv[4])  | ((uint32_t)f2bf(vv[5])  << 16);
        lo.w = (uint32_t)f2bf(vv[6])  | ((uint32_t)f2bf(vv[7])  << 16);
        hi.x = (uint32_t)f2bf(vv[8])  | ((uint32_t)f2bf(vv[9])  << 16);
        hi.y = (uint32_t)f2bf(vv[10]) | ((uint32_t)f2bf(vv[11]) << 16);
        hi.z = (uint32_t)f2bf(vv[12]) | ((uint32_t)f2bf(vv[13]) << 16);
        hi.w = (uint32_t)f2bf(vv[14]) | ((uint32_t)f2bf(vv[15]) << 16);
        ushort* dst = h_t + ((size_t)b * S_ + sc * 256 + t) * C_ + c0;
        *(uint4*)dst = lo;
        *(uint4*)(dst + 8) = hi;
    }
}

// ---------------- GEMM: out[o][s] = sum_c W[o][c] * Bt[s][c] (+bias, modes) ----------------
// MODE 0: bf16 out transposed [B][S][C], val=(acc+bias)*scale   (q_t, k_t)
// MODE 1: bf16 out natural    [B][C][S], val=acc+bias           (v)
// MODE 2: f32  out natural    [B][C][S], val=x+acc+bias         (final)
template <int MODE>
__global__ __launch_bounds__(256, 2) void gemm_kernel(
        const ushort* __restrict__ A,     // [512][512] bf16 weights
        const ushort* __restrict__ Bt,    // [B][4096][512] bf16
        const float* __restrict__ bias,
        void* __restrict__ outp,
        const float* __restrict__ xres,
        float scale) {
    int bb = blockIdx.z;
    int m0 = blockIdx.y * 64;
    int n0 = blockIdx.x * 128;
    const ushort* Bp = Bt + (size_t)bb * S_ * C_ + (size_t)n0 * C_;
    __shared__ ushort Al[64 * 64];    // swizzled [64][64]
    __shared__ ushort Bl[128 * 64];   // swizzled [128][64]
    int t = threadIdx.x, lane = t & 63, wid = t >> 6;
    int wm = (wid >> 1) * 32, wn = (wid & 1) * 64;
    f32x4 acc[2][4] = {};
    for (int k0 = 0; k0 < 512; k0 += 64) {
        #pragma unroll
        for (int i = 0; i < 2; i++) {
            int cid = t + i * 256;
            int row = cid >> 3, cc = cid & 7;
            uint4 d = *(const uint4*)(A + (size_t)(m0 + row) * 512 + k0 + cc * 8);
            *(uint4*)((char*)Al + row * 128 + ((cc * 16) ^ ((row & 7) << 4))) = d;
        }
        #pragma unroll
        for (int i = 0; i < 4; i++) {
            int cid = t + i * 256;
            int row = cid >> 3, cc = cid & 7;
            uint4 d = *(const uint4*)(Bp + (size_t)row * 512 + k0 + cc * 8);
            *(uint4*)((char*)Bl + row * 128 + ((cc * 16) ^ ((row & 7) << 4))) = d;
        }
        __syncthreads();
        #pragma unroll
        for (int ks = 0; ks < 2; ks++) {
            short8 af[2], bfrag[4];
            #pragma unroll
            for (int i = 0; i < 2; i++) {
                int row = wm + i * 16 + (lane & 15);
                af[i] = *(const short8*)((char*)Al + row * 128 + ((ks * 64 + (lane >> 4) * 16) ^ ((row & 7) << 4)));
            }
            #pragma unroll
            for (int j = 0; j < 4; j++) {
                int row = wn + j * 16 + (lane & 15);
                bfrag[j] = *(const short8*)((char*)Bl + row * 128 + ((ks * 64 + (lane >> 4) * 16) ^ ((row & 7) << 4)));
            }
            #pragma unroll
            for (int i = 0; i < 2; i++)
                #pragma unroll
                for (int j = 0; j < 4; j++)
                    acc[i][j] = __builtin_amdgcn_mfma_f32_16x16x32_bf16(af[i], bfrag[j], acc[i][j], 0, 0, 0);
        }
        __syncthreads();
    }
    int rr = (lane >> 4) * 4;
    #pragma unroll
    for (int i = 0; i < 2; i++) {
        int mb = m0 + wm + i * 16 + rr;
        float bs[4];
        #pragma unroll
        for (int r = 0; r < 4; r++) bs[r] = bias[mb + r];
        #pragma unroll
        for (int j = 0; j < 4; j++) {
            int n = n0 + wn + j * 16 + (lane & 15);
            if (MODE == 0) {
                ushort* O = (ushort*)outp + (size_t)bb * S_ * C_ + (size_t)n * C_ + mb;
                uint2 pp;
                pp.x = (uint32_t)f2bf((acc[i][j][0] + bs[0]) * scale) |
                       ((uint32_t)f2bf((acc[i][j][1] + bs[1]) * scale) << 16);
                pp.y = (uint32_t)f2bf((acc[i][j][2] + bs[2]) * scale) |
                       ((uint32_t)f2bf((acc[i][j][3] + bs[3]) * scale) << 16);
                *(uint2*)O = pp;
            } else if (MODE == 1) {
                ushort* O = (ushort*)outp + (size_t)bb * C_ * S_ + (size_t)mb * S_ + n;
                #pragma unroll
                for (int r = 0; r < 4; r++) O[(size_t)r * S_] = f2bf(acc[i][j][r] + bs[r]);
            } else {
                float* O = (float*)outp + (size_t)bb * C_ * S_ + (size_t)mb * S_ + n;
                const float* X = xres + (size_t)bb * C_ * S_ + (size_t)mb * S_ + n;
                #pragma unroll
                for (int r = 0; r < 4; r++) O[(size_t)r * S_] = X[(size_t)r * S_] + acc[i][j][r] + bs[r];
            }
        }
    }
}

// ---------------- Flash attention ----------------
// grid (64 q-blocks, 4 batch), 512 threads (8 waves). QBLK=64, KVBLK=32, D=C=512.
// q_t,k_t: [B][S][C] bf16 (q pre-scaled).  v: [B][C][S] bf16.  ao_t: [B][S][C] bf16.
__global__ __launch_bounds__(512, 2) void attn_kernel(const ushort* __restrict__ q_t,
        const ushort* __restrict__ k_t, const ushort* __restrict__ v,
        ushort* __restrict__ ao_t) {
    constexpr int KVBLK = 32, NIT = S_ / KVBLK;
    int qb = blockIdx.x, bb = blockIdx.y;
    int s0 = qb * 64;
    const ushort* qp = q_t + (size_t)bb * S_ * C_;
    const ushort* kp = k_t + (size_t)bb * S_ * C_;
    const ushort* vp = v   + (size_t)bb * C_ * S_;

    extern __shared__ char lds[];
    ushort* K_lds = (ushort*)lds;                       // [32][512] swizzled (32768 B)
    ushort* V_lds = (ushort*)(lds + 32768);             // [512][40]           (40960 B)
    float*  S_lds = (float*)(lds + 73728);              // [64][36] f32        (9216 B)
    ushort* P_lds = (ushort*)(lds + 82944);             // [64][40] bf16       (5120 B)
    float*  st_m  = (float*)(lds + 88064);
    float*  st_l  = st_m + 64;
    float*  st_f  = st_m + 128;
    ushort* O_lds = (ushort*)lds;                       // epilogue reuse [64][520]

    int t = threadIdx.x, lane = t & 63, wid = t >> 6;
    int mt = wid >> 1, nt = wid & 1;

    if (t < 64) { st_m[t] = -1e30f; st_l[t] = 0.f; st_f[t] = 1.f; }

    // Q fragments in registers: rows mt*16..+15, all K=512
    short8 qf[16];
    {
        const ushort* qrow = qp + (size_t)(s0 + mt * 16 + (lane & 15)) * C_ + (lane >> 4) * 8;
        #pragma unroll
        for (int ks = 0; ks < 16; ks++)
            qf[ks] = *(const short8*)(qrow + ks * 32);
    }
    f32x4 o_[4][4] = {};
    __syncthreads();

    for (int it = 0; it < NIT; it++) {
        int kv0 = it * KVBLK;
        // stage K (swizzled) : thread -> row t>>4, 4 chunks of 16B
        {
            int row = t >> 4;
            const ushort* g = kp + (size_t)(kv0 + row) * C_;
            int sw = (row & 7) << 4;
            char* db = (char*)K_lds + row * 1024;
            #pragma unroll
            for (int i = 0; i < 4; i++) {
                int cc = (t & 15) + 16 * i;
                uint4 d = *(const uint4*)(g + cc * 8);
                *(uint4*)(db + ((cc * 16) ^ sw)) = d;
            }
        }
        // stage V transposed-tile: thread -> channel row t, 32 kv elems
        {
            const ushort* g = vp + (size_t)t * S_ + kv0;
            char* dst = (char*)V_lds + t * 80;
            #pragma unroll
            for (int j = 0; j < 4; j++) {
                uint4 d = *(const uint4*)(g + j * 8);
                *(uint4*)(dst + j * 16) = d;
            }
        }
        __syncthreads();
        // S = Q Kt : wave computes 16x16 tile (mt, nt)
        f32x4 s4 = {0.f, 0.f, 0.f, 0.f};
        {
            int krow = nt * 16 + (lane & 15);
            const char* kb = (const char*)K_lds + krow * 1024;
            int sw = (krow & 7) << 4;
            int lofs = (lane >> 4) * 16;
            #pragma unroll
            for (int ks = 0; ks < 16; ks++) {
                short8 bfrag = *(const short8*)(kb + ((ks * 64 + lofs) ^ sw));
                s4 = __builtin_amdgcn_mfma_f32_16x16x32_bf16(qf[ks], bfrag, s4, 0, 0, 0);
            }
        }
        {
            int row = mt * 16 + (lane >> 4) * 4;
            int col = nt * 16 + (lane & 15);
            #pragma unroll
            for (int r = 0; r < 4; r++)
                S_lds[(row + r) * 36 + col] = s4[r];
        }
        __syncthreads();
        // online softmax: 8 threads per row
        {
            int row = t >> 3, j0 = t & 7;
            float sv[4];
            float mx = -1e30f;
            #pragma unroll
            for (int i = 0; i < 4; i++) { sv[i] = S_lds[row * 36 + j0 + 8 * i]; mx = fmaxf(mx, sv[i]); }
            mx = fmaxf(mx, __shfl_xor(mx, 1));
            mx = fmaxf(mx, __shfl_xor(mx, 2));
            mx = fmaxf(mx, __shfl_xor(mx, 4));
            float mold = st_m[row];
            float mnew = fmaxf(mold, mx);
            float ps = 0.f;
            ushort pb[4];
            #pragma unroll
            for (int i = 0; i < 4; i++) {
                float p = __expf(sv[i] - mnew);
                ps += p;
                pb[i] = f2bf(p);
            }
            ps += __shfl_xor(ps, 1); ps += __shfl_xor(ps, 2); ps += __shfl_xor(ps, 4);
            float f = __expf(mold - mnew);
            if (j0 == 0) {
                st_m[row] = mnew;
                st_l[row] = st_l[row] * f + ps;
                st_f[row] = f;
            }
            #pragma unroll
            for (int i = 0; i < 4; i++)
                P_lds[row * 40 + j0 + 8 * i] = pb[i];
        }
        __syncthreads();
        // rescale O and accumulate P @ V
        {
            int rbase = (lane >> 4) * 4;
            #pragma unroll
            for (int mt2 = 0; mt2 < 4; mt2++) {
                float fr[4];
                #pragma unroll
                for (int r = 0; r < 4; r++) fr[r] = st_f[mt2 * 16 + rbase + r];
                #pragma unroll
                for (int nt2 = 0; nt2 < 4; nt2++)
                    #pragma unroll
                    for (int r = 0; r < 4; r++)
                        o_[mt2][nt2][r] *= fr[r];
            }
            int lofs = (lane >> 4) * 16;
            short8 vb[4];
            #pragma unroll
            for (int nt2 = 0; nt2 < 4; nt2++) {
                int c = wid * 64 + nt2 * 16 + (lane & 15);
                vb[nt2] = *(const short8*)((const char*)V_lds + c * 80 + lofs);
            }
            #pragma unroll
            for (int mt2 = 0; mt2 < 4; mt2++) {
                int prow = mt2 * 16 + (lane & 15);
                short8 af = *(const short8*)((const char*)P_lds + prow * 80 + lofs);
                #pragma unroll
                for (int nt2 = 0; nt2 < 4; nt2++)
                    o_[mt2][nt2] = __builtin_amdgcn_mfma_f32_16x16x32_bf16(af, vb[nt2], o_[mt2][nt2], 0, 0, 0);
            }
        }
        __syncthreads();
    }
    // epilogue: divide by l, bounce through LDS, coalesced store
    {
        int rbase = (lane >> 4) * 4;
        #pragma unroll
        for (int mt2 = 0; mt2 < 4; mt2++) {
            float rl[4];
            #pragma unroll
            for (int r = 0; r < 4; r++) rl[r] = 1.0f / st_l[mt2 * 16 + rbase + r];
            #pragma unroll
            for (int nt2 = 0; nt2 < 4; nt2++) {
                int col = wid * 64 + nt2 * 16 + (lane & 15);
                int rowb = mt2 * 16 + rbase;
                #pragma unroll
                for (int r = 0; r < 4; r++)
                    O_lds[(rowb + r) * 520 + col] = f2bf(o_[mt2][nt2][r] * rl[r]);
            }
        }
    }
    __syncthreads();
    {
        int row = t >> 3, c0 = (t & 7) * 64;
        const ushort* src = O_lds + row * 520 + c0;
        ushort* dst = ao_t + ((size_t)bb * S_ + s0 + row) * C_ + c0;
        #pragma unroll
        for (int j = 0; j < 8; j++) {
            uint4 d = *(const uint4*)(src + j * 8);
            *(uint4*)(dst + j * 8) = d;
        }
    }
}

extern "C" void kernel_launch(void* const* d_in, const int* in_sizes, int n_in,
                              void* d_out, int out_size, void* d_ws, size_t ws_size,
                              hipStream_t stream) {
    const float* x  = (const float*)d_in[0];
    const float* gg = (const float*)d_in[1];
    const float* gb = (const float*)d_in[2];
    const float* wq = (const float*)d_in[3];
    const float* bq = (const float*)d_in[4];
    const float* wk = (const float*)d_in[5];
    const float* bk = (const float*)d_in[6];
    const float* wv = (const float*)d_in[7];
    const float* bv = (const float*)d_in[8];
    const float* wo = (const float*)d_in[9];
    const float* bo = (const float*)d_in[10];
    float* out = (float*)d_out;

    char* ws = (char*)d_ws;
    const size_t BUF = (size_t)B_ * S_ * C_ * 2;    // 16 MB bf16 buffer
    ushort* h_t  = (ushort*)(ws);
    ushort* q_t  = (ushort*)(ws + BUF);
    ushort* k_t  = (ushort*)(ws + 2 * BUF);
    ushort* v_n  = (ushort*)(ws + 3 * BUF);
    ushort* ao_t = (ushort*)(ws + 4 * BUF);
    ushort* wb   = (ushort*)(ws + 5 * BUF);         // 4 x 262144 bf16
    float* stats = (float*)(ws + 5 * BUF + 4 * 524288);

    wconv_kernel<<<1024, 256, 0, stream>>>(wq, wk, wv, wo, wb);
    gn_stats_kernel<<<128, 512, 0, stream>>>(x, stats);
    gn_apply_kernel<<<dim3(16, 32, B_), 256, 0, stream>>>(x, gg, gb, stats, h_t);

    dim3 ggrid(32, 8, B_);
    gemm_kernel<0><<<ggrid, 256, 0, stream>>>(wb,          h_t, bq, (void*)q_t, nullptr, SCALE_);
    gemm_kernel<0><<<ggrid, 256, 0, stream>>>(wb + 262144, h_t, bk, (void*)k_t, nullptr, 1.0f);
    gemm_kernel<1><<<ggrid, 256, 0, stream>>>(wb + 524288, h_t, bv, (void*)v_n, nullptr, 1.0f);

    attn_kernel<<<dim3(64, B_), 512, 88832, stream>>>(q_t, k_t, v_n, ao_t);

    gemm_kernel<2><<<ggrid, 256, 0, stream>>>(wb + 786432, ao_t, bo, (void*)out, x, 1.0f);
}

// Round 2
// 496.988 us; speedup vs baseline: 1.2836x; 1.2836x over previous
//
#include <hip/hip_runtime.h>
#include <cstdint>
#include <cstddef>

typedef __attribute__((ext_vector_type(8))) short short8;    // bf16x8 MFMA fragment
typedef __attribute__((ext_vector_type(4))) float f32x4;     // fp32x4 accumulator
typedef __attribute__((ext_vector_type(16))) float f32x16;   // fp32x16 accumulator (32x32)

#define C_ 512
#define S_ 4096
#define B_ 4
#define EPS_ 1e-6f
#define SCALE_ 0.04419417382415922f   // 512^-0.5, folded into q

__device__ __forceinline__ ushort f2bf(float f) {
    union { float f; uint32_t u; } v; v.f = f;
    uint32_t r = v.u + 0x7FFFu + ((v.u >> 16) & 1u);
    return (ushort)(r >> 16);
}

// ---------------- weight fp32 -> bf16 ----------------
__global__ void wconv_kernel(const float* __restrict__ wq, const float* __restrict__ wk,
                             const float* __restrict__ wv, const float* __restrict__ wo,
                             ushort* __restrict__ out) {
    int i = blockIdx.x * 256 + threadIdx.x;   // grid covers exactly 262144
    out[i]          = f2bf(wq[i]);
    out[262144 + i] = f2bf(wk[i]);
    out[524288 + i] = f2bf(wv[i]);
    out[786432 + i] = f2bf(wo[i]);
}

// ---------------- GroupNorm stats: one block per (b,g) ----------------
__global__ __launch_bounds__(512) void gn_stats_kernel(const float* __restrict__ x,
                                                       float* __restrict__ stats) {
    int bg = blockIdx.x;                       // b*32+g ; channels contiguous
    const float* xp = x + (size_t)bg * 16 * S_;
    float sum = 0.f, ss = 0.f;
    for (int i = threadIdx.x; i < 16 * S_; i += 512) {
        float v = xp[i];
        sum += v; ss += v * v;
    }
    #pragma unroll
    for (int off = 32; off; off >>= 1) {
        sum += __shfl_down(sum, off);
        ss  += __shfl_down(ss, off);
    }
    __shared__ float r0[8], r1[8];
    int wid = threadIdx.x >> 6;
    if ((threadIdx.x & 63) == 0) { r0[wid] = sum; r1[wid] = ss; }
    __syncthreads();
    if (threadIdx.x == 0) {
        float ts = 0.f, tq = 0.f;
        #pragma unroll
        for (int w = 0; w < 8; w++) { ts += r0[w]; tq += r1[w]; }
        float mean = ts / 65536.f;
        float var  = tq / 65536.f - mean * mean;
        stats[bg * 2]     = mean;
        stats[bg * 2 + 1] = rsqrtf(var + EPS_);
    }
}

// ---------------- GroupNorm apply + transpose to h_t[s][c] bf16 ----------------
__global__ __launch_bounds__(256) void gn_apply_kernel(const float* __restrict__ x,
        const float* __restrict__ gamma, const float* __restrict__ beta,
        const float* __restrict__ stats, ushort* __restrict__ h_t) {
    int sc = blockIdx.x, g = blockIdx.y, b = blockIdx.z;
    int c0 = g * 16;
    int bg = b * 32 + g;
    float mean = stats[bg * 2], rstd = stats[bg * 2 + 1];
    int t = threadIdx.x;
    __shared__ float tile[16][257];
    const float* xp = x + ((size_t)b * C_ + c0) * S_ + sc * 256;
    {
        int c = t >> 4, s0 = (t & 15) * 4;
        const float* src = xp + (size_t)c * S_;
        #pragma unroll
        for (int j = 0; j < 4; j++) {
            float4 d = *(const float4*)(src + s0 + 64 * j);
            tile[c][s0 + 64 * j + 0] = d.x;
            tile[c][s0 + 64 * j + 1] = d.y;
            tile[c][s0 + 64 * j + 2] = d.z;
            tile[c][s0 + 64 * j + 3] = d.w;
        }
    }
    __syncthreads();
    {
        float vv[16];
        #pragma unroll
        for (int ci = 0; ci < 16; ci++) {
            float a = rstd * gamma[c0 + ci];
            float bb2 = beta[c0 + ci] - mean * a;
            vv[ci] = tile[ci][t] * a + bb2;
        }
        uint4 lo, hi;
        lo.x = (uint32_t)f2bf(vv[0])  | ((uint32_t)f2bf(vv[1])  << 16);
        lo.y = (uint32_t)f2bf(vv[2])  | ((uint32_t)f2bf(vv[3])  << 16);
        lo.z = (uint32_t)f2bf(vv[4])  | ((uint32_t)f2bf(vv[5])  << 16);
        lo.w = (uint32_t)f2bf(vv[6])  | ((uint32_t)f2bf(vv[7])  << 16);
        hi.x = (uint32_t)f2bf(vv[8])  | ((uint32_t)f2bf(vv[9])  << 16);
        hi.y = (uint32_t)f2bf(vv[10]) | ((uint32_t)f2bf(vv[11]) << 16);
        hi.z = (uint32_t)f2bf(vv[12]) | ((uint32_t)f2bf(vv[13]) << 16);
        hi.w = (uint32_t)f2bf(vv[14]) | ((uint32_t)f2bf(vv[15]) << 16);
        ushort* dst = h_t + ((size_t)b * S_ + sc * 256 + t) * C_ + c0;
        *(uint4*)dst = lo;
        *(uint4*)(dst + 8) = hi;
    }
}

// ---------------- GEMM: out[o][s] = sum_c W[o][c] * Bt[s][c] (+bias, modes) ----------------
template <int MODE>
__global__ __launch_bounds__(256, 2) void gemm_kernel(
        const ushort* __restrict__ A,     // [512][512] bf16 weights
        const ushort* __restrict__ Bt,    // [B][4096][512] bf16
        const float* __restrict__ bias,
        void* __restrict__ outp,
        const float* __restrict__ xres,
        float scale) {
    int bb = blockIdx.z;
    int m0 = blockIdx.y * 64;
    int n0 = blockIdx.x * 128;
    const ushort* Bp = Bt + (size_t)bb * S_ * C_ + (size_t)n0 * C_;
    __shared__ ushort Al[64 * 64];    // swizzled [64][64]
    __shared__ ushort Bl[128 * 64];   // swizzled [128][64]
    int t = threadIdx.x, lane = t & 63, wid = t >> 6;
    int wm = (wid >> 1) * 32, wn = (wid & 1) * 64;
    f32x4 acc[2][4] = {};
    for (int k0 = 0; k0 < 512; k0 += 64) {
        #pragma unroll
        for (int i = 0; i < 2; i++) {
            int cid = t + i * 256;
            int row = cid >> 3, cc = cid & 7;
            uint4 d = *(const uint4*)(A + (size_t)(m0 + row) * 512 + k0 + cc * 8);
            *(uint4*)((char*)Al + row * 128 + ((cc * 16) ^ ((row & 7) << 4))) = d;
        }
        #pragma unroll
        for (int i = 0; i < 4; i++) {
            int cid = t + i * 256;
            int row = cid >> 3, cc = cid & 7;
            uint4 d = *(const uint4*)(Bp + (size_t)row * 512 + k0 + cc * 8);
            *(uint4*)((char*)Bl + row * 128 + ((cc * 16) ^ ((row & 7) << 4))) = d;
        }
        __syncthreads();
        #pragma unroll
        for (int ks = 0; ks < 2; ks++) {
            short8 af[2], bfrag[4];
            #pragma unroll
            for (int i = 0; i < 2; i++) {
                int row = wm + i * 16 + (lane & 15);
                af[i] = *(const short8*)((char*)Al + row * 128 + ((ks * 64 + (lane >> 4) * 16) ^ ((row & 7) << 4)));
            }
            #pragma unroll
            for (int j = 0; j < 4; j++) {
                int row = wn + j * 16 + (lane & 15);
                bfrag[j] = *(const short8*)((char*)Bl + row * 128 + ((ks * 64 + (lane >> 4) * 16) ^ ((row & 7) << 4)));
            }
            #pragma unroll
            for (int i = 0; i < 2; i++)
                #pragma unroll
                for (int j = 0; j < 4; j++)
                    acc[i][j] = __builtin_amdgcn_mfma_f32_16x16x32_bf16(af[i], bfrag[j], acc[i][j], 0, 0, 0);
        }
        __syncthreads();
    }
    int rr = (lane >> 4) * 4;
    #pragma unroll
    for (int i = 0; i < 2; i++) {
        int mb = m0 + wm + i * 16 + rr;
        float bs[4];
        #pragma unroll
        for (int r = 0; r < 4; r++) bs[r] = bias[mb + r];
        #pragma unroll
        for (int j = 0; j < 4; j++) {
            int n = n0 + wn + j * 16 + (lane & 15);
            if (MODE == 0) {
                ushort* O = (ushort*)outp + (size_t)bb * S_ * C_ + (size_t)n * C_ + mb;
                uint2 pp;
                pp.x = (uint32_t)f2bf((acc[i][j][0] + bs[0]) * scale) |
                       ((uint32_t)f2bf((acc[i][j][1] + bs[1]) * scale) << 16);
                pp.y = (uint32_t)f2bf((acc[i][j][2] + bs[2]) * scale) |
                       ((uint32_t)f2bf((acc[i][j][3] + bs[3]) * scale) << 16);
                *(uint2*)O = pp;
            } else if (MODE == 1) {
                ushort* O = (ushort*)outp + (size_t)bb * C_ * S_ + (size_t)mb * S_ + n;
                #pragma unroll
                for (int r = 0; r < 4; r++) O[(size_t)r * S_] = f2bf(acc[i][j][r] + bs[r]);
            } else {
                float* O = (float*)outp + (size_t)bb * C_ * S_ + (size_t)mb * S_ + n;
                const float* X = xres + (size_t)bb * C_ * S_ + (size_t)mb * S_ + n;
                #pragma unroll
                for (int r = 0; r < 4; r++) O[(size_t)r * S_] = X[(size_t)r * S_] + acc[i][j][r] + bs[r];
            }
        }
    }
}

// ---------------- Flash attention, 32x32x16 MFMA, KVBLK=64, V direct-from-global ----
// grid (64 q-blocks, 4 batch), 512 threads (8 waves). QBLK=64, D=C=512.
// q_t,k_t: [B][S][C] bf16 (q pre-scaled).  v: [B][C][S] bf16.  ao_t: [B][S][C] bf16.
//
// LDS map (110336 B):
//   K_lds : [64 kv][1024B] XOR-swizzled (byte ^= (row&7)<<4 within 128B blocks)  0..65536
//   S_lds : [2 c-half][64 q][68] f32 partial scores                         65536..100352
//   P_lds : [64 q][72] bf16 (row stride 144B, conflict-free for 32x32 A-frag) 100352..109568
//   st_m/l/f : [64] f32 each                                                109568..110336
#define KLDS_SZ  65536
#define SLDS_OFF 65536
#define PLDS_OFF 100352
#define STM_OFF  109568

__device__ __forceinline__ void stage_k(const ushort* kp, int kv0, int wid, int lane, char* K_lds) {
    #pragma unroll
    for (int p = 0; p < 8; p++) {
        int row = wid * 8 + p;
        // pre-swizzled global source (m173): LDS dest is linear (base + lane*16)
        const char* src = (const char*)(kp + (size_t)(kv0 + row) * C_) + ((lane * 16) ^ ((row & 7) << 4));
        __builtin_amdgcn_global_load_lds(
            (const __attribute__((address_space(1))) unsigned int*)src,
            (__attribute__((address_space(3))) unsigned int*)(K_lds + row * 1024),
            16, 0, 0);
    }
}

__global__ __launch_bounds__(512, 2) void attn_kernel(const ushort* __restrict__ q_t,
        const ushort* __restrict__ k_t, const ushort* __restrict__ v,
        ushort* __restrict__ ao_t) {
    constexpr int NIT = S_ / 64;
    int qb = blockIdx.x, bb = blockIdx.y;
    int s0 = qb * 64;
    const ushort* qp = q_t + (size_t)bb * S_ * C_;
    const ushort* kp = k_t + (size_t)bb * S_ * C_;
    const ushort* vp = v   + (size_t)bb * C_ * S_;

    extern __shared__ char lds[];
    char*  K_lds = lds;
    float* S_lds = (float*)(lds + SLDS_OFF);
    char*  P_lds = lds + PLDS_OFF;
    float* st_m  = (float*)(lds + STM_OFF);
    float* st_l  = st_m + 64;
    float* st_f  = st_m + 128;

    int t = threadIdx.x, lane = t & 63, wid = t >> 6;
    int l31 = lane & 31, lh = lane >> 5;
    int qt = (wid >> 2) & 1, nt = (wid >> 1) & 1, ch = wid & 1;

    if (t < 64) { st_m[t] = -1e30f; st_l[t] = 0.f; }

    // Q fragments in registers: wave covers rows qt*32..+31, c-half ch (256 c)
    short8 qf[16];
    {
        const ushort* qrow = qp + (size_t)(s0 + qt * 32 + l31) * C_ + ch * 256 + lh * 8;
        #pragma unroll
        for (int ks = 0; ks < 16; ks++)
            qf[ks] = *(const short8*)(qrow + ks * 16);
    }
    f32x16 o_[2][2] = {};

    stage_k(kp, 0, wid, lane, K_lds);
    __syncthreads();

    for (int it = 0; it < NIT; it++) {
        int kv0 = it * 64;
        // ---- S-phase: wave (qt,nt,ch) computes partial S[qt-tile][nt-tile] over c-half
        f32x16 sacc = {};
        {
            int krow = nt * 32 + l31;
            const char* kb = K_lds + krow * 1024;
            int sw = (krow & 7) << 4;
            int cb0 = ch * 512 + lh * 16;
            #pragma unroll
            for (int ks = 0; ks < 16; ks++) {
                short8 kf = *(const short8*)(kb + ((cb0 + ks * 32) ^ sw));
                sacc = __builtin_amdgcn_mfma_f32_32x32x16_bf16(qf[ks], kf, sacc, 0, 0, 0);
            }
        }
        {
            float* Sp = S_lds + (size_t)(ch * 64 + qt * 32) * 68 + nt * 32 + l31;
            #pragma unroll
            for (int r = 0; r < 16; r++) {
                int qrow = (r & 3) + 8 * (r >> 2) + 4 * lh;
                Sp[qrow * 68] = sacc[r];
            }
        }
        __syncthreads();   // S visible; K_lds reads done -> safe to restage

        if (it + 1 < NIT)
            stage_k(kp, kv0 + 64, wid, lane, K_lds);   // async; drains at end-of-iter barrier

        // ---- softmax: 8 threads per q-row, thread covers kv j*8..+7
        {
            int row = t >> 3, j = t & 7;
            const float* s0p = S_lds + (size_t)row * 68 + j * 8;
            const float* s1p = s0p + 64 * 68;
            float sv[8];
            #pragma unroll
            for (int i = 0; i < 8; i++) sv[i] = s0p[i] + s1p[i];
            float mx = sv[0];
            #pragma unroll
            for (int i = 1; i < 8; i++) mx = fmaxf(mx, sv[i]);
            mx = fmaxf(mx, __shfl_xor(mx, 1));
            mx = fmaxf(mx, __shfl_xor(mx, 2));
            mx = fmaxf(mx, __shfl_xor(mx, 4));
            float mold = st_m[row];
            float mnew = fmaxf(mold, mx);
            float ps = 0.f;
            uint32_t pk[4];
            #pragma unroll
            for (int i = 0; i < 4; i++) {
                float p0 = __expf(sv[2 * i]     - mnew);
                float p1 = __expf(sv[2 * i + 1] - mnew);
                ps += p0 + p1;
                pk[i] = (uint32_t)f2bf(p0) | ((uint32_t)f2bf(p1) << 16);
            }
            *(uint4*)(P_lds + (size_t)row * 144 + j * 16) = *(uint4*)pk;
            ps += __shfl_xor(ps, 1); ps += __shfl_xor(ps, 2); ps += __shfl_xor(ps, 4);
            float f = __expf(mold - mnew);
            if (j == 0) {
                st_m[row] = mnew;
                st_l[row] = st_l[row] * f + ps;
                st_f[row] = f;
            }
        }
        __syncthreads();

        // ---- PV: wave owns d-slice wid*64 (2 d-tiles of 32); A=P from LDS, B=V from global
        {
            // rescale O by f (broadcast LDS reads)
            #pragma unroll
            for (int qt2 = 0; qt2 < 2; qt2++) {
                float fr[16];
                #pragma unroll
                for (int r = 0; r < 16; r++)
                    fr[r] = st_f[qt2 * 32 + (r & 3) + 8 * (r >> 2) + 4 * lh];
                #pragma unroll
                for (int dt = 0; dt < 2; dt++)
                    #pragma unroll
                    for (int r = 0; r < 16; r++)
                        o_[qt2][dt][r] *= fr[r];
            }
            short8 vb[2][4];
            const ushort* vdb = vp + (size_t)(wid * 64 + l31) * S_ + kv0 + lh * 8;
            #pragma unroll
            for (int dt = 0; dt < 2; dt++)
                #pragma unroll
                for (int ks2 = 0; ks2 < 4; ks2++)
                    vb[dt][ks2] = *(const short8*)(vdb + (size_t)dt * 32 * S_ + ks2 * 16);
            short8 pa[2][4];
            #pragma unroll
            for (int qt2 = 0; qt2 < 2; qt2++)
                #pragma unroll
                for (int ks2 = 0; ks2 < 4; ks2++)
                    pa[qt2][ks2] = *(const short8*)(P_lds + (size_t)(qt2 * 32 + l31) * 144 + ks2 * 32 + lh * 16);
            #pragma unroll
            for (int qt2 = 0; qt2 < 2; qt2++)
                #pragma unroll
                for (int dt = 0; dt < 2; dt++)
                    #pragma unroll
                    for (int ks2 = 0; ks2 < 4; ks2++)
                        o_[qt2][dt] = __builtin_amdgcn_mfma_f32_32x32x16_bf16(pa[qt2][ks2], vb[dt][ks2], o_[qt2][dt], 0, 0, 0);
        }
        __syncthreads();   // P/S reuse safe; implicit vmcnt(0) drains K staging
    }

    // ---- epilogue: O / l -> bf16 -> ao_t[s][c]
    #pragma unroll
    for (int qt2 = 0; qt2 < 2; qt2++) {
        float rl[16];
        #pragma unroll
        for (int r = 0; r < 16; r++)
            rl[r] = 1.0f / st_l[qt2 * 32 + (r & 3) + 8 * (r >> 2) + 4 * lh];
        #pragma unroll
        for (int dt = 0; dt < 2; dt++) {
            int d = wid * 64 + dt * 32 + l31;
            #pragma unroll
            for (int r = 0; r < 16; r++) {
                int q = qt2 * 32 + (r & 3) + 8 * (r >> 2) + 4 * lh;
                ao_t[((size_t)bb * S_ + s0 + q) * C_ + d] = f2bf(o_[qt2][dt][r] * rl[r]);
            }
        }
    }
}

extern "C" void kernel_launch(void* const* d_in, const int* in_sizes, int n_in,
                              void* d_out, int out_size, void* d_ws, size_t ws_size,
                              hipStream_t stream) {
    const float* x  = (const float*)d_in[0];
    const float* gg = (const float*)d_in[1];
    const float* gb = (const float*)d_in[2];
    const float* wq = (const float*)d_in[3];
    const float* bq = (const float*)d_in[4];
    const float* wk = (const float*)d_in[5];
    const float* bk = (const float*)d_in[6];
    const float* wv = (const float*)d_in[7];
    const float* bv = (const float*)d_in[8];
    const float* wo = (const float*)d_in[9];
    const float* bo = (const float*)d_in[10];
    float* out = (float*)d_out;

    char* ws = (char*)d_ws;
    const size_t BUF = (size_t)B_ * S_ * C_ * 2;    // 16 MB bf16 buffer
    ushort* h_t  = (ushort*)(ws);
    ushort* q_t  = (ushort*)(ws + BUF);
    ushort* k_t  = (ushort*)(ws + 2 * BUF);
    ushort* v_n  = (ushort*)(ws + 3 * BUF);
    ushort* ao_t = (ushort*)(ws + 4 * BUF);
    ushort* wb   = (ushort*)(ws + 5 * BUF);         // 4 x 262144 bf16
    float* stats = (float*)(ws + 5 * BUF + 4 * 524288);

    wconv_kernel<<<1024, 256, 0, stream>>>(wq, wk, wv, wo, wb);
    gn_stats_kernel<<<128, 512, 0, stream>>>(x, stats);
    gn_apply_kernel<<<dim3(16, 32, B_), 256, 0, stream>>>(x, gg, gb, stats, h_t);

    dim3 ggrid(32, 8, B_);
    gemm_kernel<0><<<ggrid, 256, 0, stream>>>(wb,          h_t, bq, (void*)q_t, nullptr, SCALE_);
    gemm_kernel<0><<<ggrid, 256, 0, stream>>>(wb + 262144, h_t, bk, (void*)k_t, nullptr, 1.0f);
    gemm_kernel<1><<<ggrid, 256, 0, stream>>>(wb + 524288, h_t, bv, (void*)v_n, nullptr, 1.0f);

    attn_kernel<<<dim3(64, B_), 512, 110336, stream>>>(q_t, k_t, v_n, ao_t);

    gemm_kernel<2><<<ggrid, 256, 0, stream>>>(wb + 786432, ao_t, bo, (void*)out, x, 1.0f);
}

// Round 3
// 467.411 us; speedup vs baseline: 1.3648x; 1.0633x over previous
//
#include <hip/hip_runtime.h>
#include <cstdint>
#include <cstddef>

typedef __attribute__((ext_vector_type(8))) short short8;      // bf16x8 MFMA fragment
typedef __attribute__((ext_vector_type(8))) _Float16 half8;    // f16x8 LDS tile
typedef __attribute__((ext_vector_type(4))) float f32x4;       // fp32x4
typedef __attribute__((ext_vector_type(16))) float f32x16;     // fp32x16 accumulator (32x32)

#define C_ 512
#define S_ 4096
#define B_ 4
#define EPS_ 1e-6f
#define SCALE_ 0.04419417382415922f   // 512^-0.5, folded into q

__device__ __forceinline__ ushort f2bf(float f) {
    union { float f; uint32_t u; } v; v.f = f;
    uint32_t r = v.u + 0x7FFFu + ((v.u >> 16) & 1u);
    return (ushort)(r >> 16);
}

// ---------------- weight fp32 -> bf16 ----------------
__global__ void wconv_kernel(const float* __restrict__ wq, const float* __restrict__ wk,
                             const float* __restrict__ wv, const float* __restrict__ wo,
                             ushort* __restrict__ out) {
    int i = blockIdx.x * 256 + threadIdx.x;   // grid covers exactly 262144
    out[i]          = f2bf(wq[i]);
    out[262144 + i] = f2bf(wk[i]);
    out[524288 + i] = f2bf(wv[i]);
    out[786432 + i] = f2bf(wo[i]);
}

// ---------------- GroupNorm stats: one block per (b,g) ----------------
__global__ __launch_bounds__(512) void gn_stats_kernel(const float* __restrict__ x,
                                                       float* __restrict__ stats) {
    int bg = blockIdx.x;                       // b*32+g ; channels contiguous
    const float* xp = x + (size_t)bg * 16 * S_;
    float sum = 0.f, ss = 0.f;
    for (int i = threadIdx.x; i < 16 * S_; i += 512) {
        float v = xp[i];
        sum += v; ss += v * v;
    }
    #pragma unroll
    for (int off = 32; off; off >>= 1) {
        sum += __shfl_down(sum, off);
        ss  += __shfl_down(ss, off);
    }
    __shared__ float r0[8], r1[8];
    int wid = threadIdx.x >> 6;
    if ((threadIdx.x & 63) == 0) { r0[wid] = sum; r1[wid] = ss; }
    __syncthreads();
    if (threadIdx.x == 0) {
        float ts = 0.f, tq = 0.f;
        #pragma unroll
        for (int w = 0; w < 8; w++) { ts += r0[w]; tq += r1[w]; }
        float mean = ts / 65536.f;
        float var  = tq / 65536.f - mean * mean;
        stats[bg * 2]     = mean;
        stats[bg * 2 + 1] = rsqrtf(var + EPS_);
    }
}

// ---------------- GroupNorm apply + transpose to h_t[s][c] bf16 ----------------
__global__ __launch_bounds__(256) void gn_apply_kernel(const float* __restrict__ x,
        const float* __restrict__ gamma, const float* __restrict__ beta,
        const float* __restrict__ stats, ushort* __restrict__ h_t) {
    int sc = blockIdx.x, g = blockIdx.y, b = blockIdx.z;
    int c0 = g * 16;
    int bg = b * 32 + g;
    float mean = stats[bg * 2], rstd = stats[bg * 2 + 1];
    int t = threadIdx.x;
    __shared__ float tile[16][257];
    const float* xp = x + ((size_t)b * C_ + c0) * S_ + sc * 256;
    {
        int c = t >> 4, s0 = (t & 15) * 4;
        const float* src = xp + (size_t)c * S_;
        #pragma unroll
        for (int j = 0; j < 4; j++) {
            float4 d = *(const float4*)(src + s0 + 64 * j);
            tile[c][s0 + 64 * j + 0] = d.x;
            tile[c][s0 + 64 * j + 1] = d.y;
            tile[c][s0 + 64 * j + 2] = d.z;
            tile[c][s0 + 64 * j + 3] = d.w;
        }
    }
    __syncthreads();
    {
        float vv[16];
        #pragma unroll
        for (int ci = 0; ci < 16; ci++) {
            float a = rstd * gamma[c0 + ci];
            float bb2 = beta[c0 + ci] - mean * a;
            vv[ci] = tile[ci][t] * a + bb2;
        }
        uint4 lo, hi;
        lo.x = (uint32_t)f2bf(vv[0])  | ((uint32_t)f2bf(vv[1])  << 16);
        lo.y = (uint32_t)f2bf(vv[2])  | ((uint32_t)f2bf(vv[3])  << 16);
        lo.z = (uint32_t)f2bf(vv[4])  | ((uint32_t)f2bf(vv[5])  << 16);
        lo.w = (uint32_t)f2bf(vv[6])  | ((uint32_t)f2bf(vv[7])  << 16);
        hi.x = (uint32_t)f2bf(vv[8])  | ((uint32_t)f2bf(vv[9])  << 16);
        hi.y = (uint32_t)f2bf(vv[10]) | ((uint32_t)f2bf(vv[11]) << 16);
        hi.z = (uint32_t)f2bf(vv[12]) | ((uint32_t)f2bf(vv[13]) << 16);
        hi.w = (uint32_t)f2bf(vv[14]) | ((uint32_t)f2bf(vv[15]) << 16);
        ushort* dst = h_t + ((size_t)b * S_ + sc * 256 + t) * C_ + c0;
        *(uint4*)dst = lo;
        *(uint4*)(dst + 8) = hi;
    }
}

// ---------------- GEMM: out[o][s] = sum_c W[o][c] * Bt[s][c] (+bias, modes) ----------------
template <int MODE>
__global__ __launch_bounds__(256, 2) void gemm_kernel(
        const ushort* __restrict__ A,     // [512][512] bf16 weights
        const ushort* __restrict__ Bt,    // [B][4096][512] bf16
        const float* __restrict__ bias,
        void* __restrict__ outp,
        const float* __restrict__ xres,
        float scale) {
    int bb = blockIdx.z;
    int m0 = blockIdx.y * 64;
    int n0 = blockIdx.x * 128;
    const ushort* Bp = Bt + (size_t)bb * S_ * C_ + (size_t)n0 * C_;
    __shared__ ushort Al[64 * 64];    // swizzled [64][64]
    __shared__ ushort Bl[128 * 64];   // swizzled [128][64]
    int t = threadIdx.x, lane = t & 63, wid = t >> 6;
    int wm = (wid >> 1) * 32, wn = (wid & 1) * 64;
    f32x4 acc[2][4] = {};
    for (int k0 = 0; k0 < 512; k0 += 64) {
        #pragma unroll
        for (int i = 0; i < 2; i++) {
            int cid = t + i * 256;
            int row = cid >> 3, cc = cid & 7;
            uint4 d = *(const uint4*)(A + (size_t)(m0 + row) * 512 + k0 + cc * 8);
            *(uint4*)((char*)Al + row * 128 + ((cc * 16) ^ ((row & 7) << 4))) = d;
        }
        #pragma unroll
        for (int i = 0; i < 4; i++) {
            int cid = t + i * 256;
            int row = cid >> 3, cc = cid & 7;
            uint4 d = *(const uint4*)(Bp + (size_t)row * 512 + k0 + cc * 8);
            *(uint4*)((char*)Bl + row * 128 + ((cc * 16) ^ ((row & 7) << 4))) = d;
        }
        __syncthreads();
        #pragma unroll
        for (int ks = 0; ks < 2; ks++) {
            short8 af[2], bfrag[4];
            #pragma unroll
            for (int i = 0; i < 2; i++) {
                int row = wm + i * 16 + (lane & 15);
                af[i] = *(const short8*)((char*)Al + row * 128 + ((ks * 64 + (lane >> 4) * 16) ^ ((row & 7) << 4)));
            }
            #pragma unroll
            for (int j = 0; j < 4; j++) {
                int row = wn + j * 16 + (lane & 15);
                bfrag[j] = *(const short8*)((char*)Bl + row * 128 + ((ks * 64 + (lane >> 4) * 16) ^ ((row & 7) << 4)));
            }
            #pragma unroll
            for (int i = 0; i < 2; i++)
                #pragma unroll
                for (int j = 0; j < 4; j++)
                    acc[i][j] = __builtin_amdgcn_mfma_f32_16x16x32_bf16(af[i], bfrag[j], acc[i][j], 0, 0, 0);
        }
        __syncthreads();
    }
    int rr = (lane >> 4) * 4;
    #pragma unroll
    for (int i = 0; i < 2; i++) {
        int mb = m0 + wm + i * 16 + rr;
        float bs[4];
        #pragma unroll
        for (int r = 0; r < 4; r++) bs[r] = bias[mb + r];
        #pragma unroll
        for (int j = 0; j < 4; j++) {
            int n = n0 + wn + j * 16 + (lane & 15);
            if (MODE == 0) {
                ushort* O = (ushort*)outp + (size_t)bb * S_ * C_ + (size_t)n * C_ + mb;
                uint2 pp;
                pp.x = (uint32_t)f2bf((acc[i][j][0] + bs[0]) * scale) |
                       ((uint32_t)f2bf((acc[i][j][1] + bs[1]) * scale) << 16);
                pp.y = (uint32_t)f2bf((acc[i][j][2] + bs[2]) * scale) |
                       ((uint32_t)f2bf((acc[i][j][3] + bs[3]) * scale) << 16);
                *(uint2*)O = pp;
            } else if (MODE == 1) {
                ushort* O = (ushort*)outp + (size_t)bb * C_ * S_ + (size_t)mb * S_ + n;
                #pragma unroll
                for (int r = 0; r < 4; r++) O[(size_t)r * S_] = f2bf(acc[i][j][r] + bs[r]);
            } else {
                float* O = (float*)outp + (size_t)bb * C_ * S_ + (size_t)mb * S_ + n;
                const float* X = xres + (size_t)bb * C_ * S_ + (size_t)mb * S_ + n;
                #pragma unroll
                for (int r = 0; r < 4; r++) O[(size_t)r * S_] = X[(size_t)r * S_] + acc[i][j][r] + bs[r];
            }
        }
    }
}

// ---------------- Flash attention, pipelined: K dbuf + raw barriers + V reg-prefetch ----
// grid (64 q-blocks, 4 batch), 512 threads (8 waves). QBLK=64, KVBLK=64, D=C=512.
// q_t,k_t: [B][S][C] bf16 (q pre-scaled).  v: [B][C][S] bf16.  ao_t: [B][S][C] bf16.
//
// LDS map (159488 B):
//   Kb0/Kb1 : 2 x [64 kv][1024B] XOR-swizzled                      0..65536..131072
//   S_lds   : [2 ch][64 q][72] f16 (stride 144B, self-swizzled) 131072..149504
//   P_lds   : [64 q][144B] bf16                                 149504..158720
//   st_m/l/f: [64] f32 each                                     158720..159488
#define KBUF_SZ  65536
#define SLDS_OFF 131072
#define PLDS_OFF 149504
#define STM_OFF  158720

__device__ __forceinline__ void stage_k(const ushort* kp, int kv0, int wid, int lane, char* Kbuf) {
    #pragma unroll
    for (int p = 0; p < 8; p++) {
        int row = wid * 8 + p;
        // pre-swizzled global source; LDS dest linear (base + lane*16)
        const char* src = (const char*)(kp + (size_t)(kv0 + row) * C_) + ((lane * 16) ^ ((row & 7) << 4));
        __builtin_amdgcn_global_load_lds(
            (const __attribute__((address_space(1))) unsigned int*)src,
            (__attribute__((address_space(3))) unsigned int*)(Kbuf + row * 1024),
            16, 0, 0);
    }
}

__global__ __launch_bounds__(512, 2) void attn_kernel(const ushort* __restrict__ q_t,
        const ushort* __restrict__ k_t, const ushort* __restrict__ v,
        ushort* __restrict__ ao_t) {
    constexpr int NIT = S_ / 64;
    int qb = blockIdx.x, bb = blockIdx.y;
    int s0 = qb * 64;
    const ushort* qp = q_t + (size_t)bb * S_ * C_;
    const ushort* kp = k_t + (size_t)bb * S_ * C_;
    const ushort* vp = v   + (size_t)bb * C_ * S_;

    extern __shared__ char lds[];
    char* Kbuf0 = lds;
    char* Kbuf1 = lds + KBUF_SZ;
    _Float16* S_lds = (_Float16*)(lds + SLDS_OFF);
    char*  P_lds = lds + PLDS_OFF;
    float* st_m  = (float*)(lds + STM_OFF);
    float* st_l  = st_m + 64;
    float* st_f  = st_m + 128;

    int t = threadIdx.x, lane = t & 63, wid = t >> 6;
    int l31 = lane & 31, lh = lane >> 5;
    int qt = (wid >> 2) & 1, nt = (wid >> 1) & 1, ch = wid & 1;

    if (t < 64) { st_m[t] = -1e30f; st_l[t] = 0.f; }

    // Q fragments in registers: wave covers rows qt*32..+31, c-half ch (256 c)
    short8 qf[16];
    {
        const ushort* qrow = qp + (size_t)(s0 + qt * 32 + l31) * C_ + ch * 256 + lh * 8;
        #pragma unroll
        for (int ks = 0; ks < 16; ks++)
            qf[ks] = *(const short8*)(qrow + ks * 16);
    }
    f32x16 o_[2][2] = {};

    stage_k(kp, 0, wid, lane, Kbuf0);
    asm volatile("s_waitcnt vmcnt(0) lgkmcnt(0)" ::: "memory");
    __builtin_amdgcn_s_barrier();
    asm volatile("" ::: "memory");

    for (int it = 0; it < NIT; it++) {
        int kv0 = it * 64;
        char* Kcur = (it & 1) ? Kbuf1 : Kbuf0;
        char* Knxt = (it & 1) ? Kbuf0 : Kbuf1;

        // ---- V prefetch into regs (consumed in PV this iter) — issue FIRST
        short8 vb[2][4];
        {
            const ushort* vdb = vp + (size_t)(wid * 64 + l31) * S_ + kv0 + lh * 8;
            #pragma unroll
            for (int dt = 0; dt < 2; dt++)
                #pragma unroll
                for (int ks2 = 0; ks2 < 4; ks2++)
                    vb[dt][ks2] = *(const short8*)(vdb + (size_t)dt * 32 * S_ + ks2 * 16);
        }
        // ---- async stage of next K tile (drained at barrier C, full-iter cover)
        if (it + 1 < NIT)
            stage_k(kp, kv0 + 64, wid, lane, Knxt);

        // ---- S-phase: wave (qt,nt,ch) computes partial S[qt][nt] over its c-half
        f32x16 sacc = {};
        {
            int krow = nt * 32 + l31;
            const char* kb = Kcur + krow * 1024;
            int sw = (krow & 7) << 4;
            int cb0 = ch * 512 + lh * 16;
            #pragma unroll
            for (int ks = 0; ks < 16; ks++) {
                short8 kf = *(const short8*)(kb + ((cb0 + ks * 32) ^ sw));
                sacc = __builtin_amdgcn_mfma_f32_32x32x16_bf16(qf[ks], kf, sacc, 0, 0, 0);
            }
        }
        {
            _Float16* Sp = S_lds + (size_t)ch * 4608 + (size_t)(qt * 32) * 72 + nt * 32 + l31;
            #pragma unroll
            for (int r = 0; r < 16; r++) {
                int qrow = (r & 3) + 8 * (r >> 2) + 4 * lh;
                Sp[qrow * 72] = (_Float16)sacc[r];
            }
        }
        asm volatile("s_waitcnt lgkmcnt(0)" ::: "memory");
        __builtin_amdgcn_s_barrier();                    // A: S visible
        asm volatile("" ::: "memory");

        // ---- softmax: 8 threads per q-row, thread covers kv j*8..+7
        {
            int row = t >> 3, j = t & 7;
            half8 h0 = *(const half8*)((const char*)S_lds + (size_t)row * 144 + j * 16);
            half8 h1 = *(const half8*)((const char*)S_lds + 9216 + (size_t)row * 144 + j * 16);
            float sv[8];
            #pragma unroll
            for (int i = 0; i < 8; i++) sv[i] = (float)h0[i] + (float)h1[i];
            float mx = sv[0];
            #pragma unroll
            for (int i = 1; i < 8; i++) mx = fmaxf(mx, sv[i]);
            mx = fmaxf(mx, __shfl_xor(mx, 1));
            mx = fmaxf(mx, __shfl_xor(mx, 2));
            mx = fmaxf(mx, __shfl_xor(mx, 4));
            float mold = st_m[row];
            float mnew = fmaxf(mold, mx);
            float ps = 0.f;
            uint32_t pk[4];
            #pragma unroll
            for (int i = 0; i < 4; i++) {
                float p0 = __expf(sv[2 * i]     - mnew);
                float p1 = __expf(sv[2 * i + 1] - mnew);
                ps += p0 + p1;
                pk[i] = (uint32_t)f2bf(p0) | ((uint32_t)f2bf(p1) << 16);
            }
            *(uint4*)(P_lds + (size_t)row * 144 + j * 16) = *(uint4*)pk;
            ps += __shfl_xor(ps, 1); ps += __shfl_xor(ps, 2); ps += __shfl_xor(ps, 4);
            float f = __expf(mold - mnew);
            if (j == 0) {
                st_m[row] = mnew;
                st_l[row] = st_l[row] * f + ps;
                st_f[row] = f;
            }
        }
        asm volatile("s_waitcnt lgkmcnt(0)" ::: "memory");
        __builtin_amdgcn_s_barrier();                    // B: P + st visible
        asm volatile("" ::: "memory");

        // ---- PV: wave owns d-slice wid*64; A=P from LDS, B=V from prefetched regs
        {
            #pragma unroll
            for (int qt2 = 0; qt2 < 2; qt2++) {
                f32x4 f0 = *(const f32x4*)(st_f + qt2 * 32 + 0  + 4 * lh);
                f32x4 f1 = *(const f32x4*)(st_f + qt2 * 32 + 8  + 4 * lh);
                f32x4 f2 = *(const f32x4*)(st_f + qt2 * 32 + 16 + 4 * lh);
                f32x4 f3 = *(const f32x4*)(st_f + qt2 * 32 + 24 + 4 * lh);
                float fr[16];
                #pragma unroll
                for (int e = 0; e < 4; e++) {
                    fr[e] = f0[e]; fr[4 + e] = f1[e]; fr[8 + e] = f2[e]; fr[12 + e] = f3[e];
                }
                #pragma unroll
                for (int dt = 0; dt < 2; dt++)
                    #pragma unroll
                    for (int r = 0; r < 16; r++)
                        o_[qt2][dt][r] *= fr[r];
            }
            short8 pa[2][4];
            #pragma unroll
            for (int qt2 = 0; qt2 < 2; qt2++)
                #pragma unroll
                for (int ks2 = 0; ks2 < 4; ks2++)
                    pa[qt2][ks2] = *(const short8*)(P_lds + (size_t)(qt2 * 32 + l31) * 144 + ks2 * 32 + lh * 16);
            #pragma unroll
            for (int qt2 = 0; qt2 < 2; qt2++)
                #pragma unroll
                for (int dt = 0; dt < 2; dt++)
                    #pragma unroll
                    for (int ks2 = 0; ks2 < 4; ks2++)
                        o_[qt2][dt] = __builtin_amdgcn_mfma_f32_32x32x16_bf16(pa[qt2][ks2], vb[dt][ks2], o_[qt2][dt], 0, 0, 0);
        }
        asm volatile("s_waitcnt vmcnt(0) lgkmcnt(0)" ::: "memory");
        __builtin_amdgcn_s_barrier();                    // C: K stage complete, P reads done
        asm volatile("" ::: "memory");
    }

    // ---- epilogue: O / l -> bf16 -> ao_t[s][c]
    #pragma unroll
    for (int qt2 = 0; qt2 < 2; qt2++) {
        f32x4 l0 = *(const f32x4*)(st_l + qt2 * 32 + 0  + 4 * lh);
        f32x4 l1 = *(const f32x4*)(st_l + qt2 * 32 + 8  + 4 * lh);
        f32x4 l2 = *(const f32x4*)(st_l + qt2 * 32 + 16 + 4 * lh);
        f32x4 l3 = *(const f32x4*)(st_l + qt2 * 32 + 24 + 4 * lh);
        float rl[16];
        #pragma unroll
        for (int e = 0; e < 4; e++) {
            rl[e] = 1.0f / l0[e]; rl[4 + e] = 1.0f / l1[e];
            rl[8 + e] = 1.0f / l2[e]; rl[12 + e] = 1.0f / l3[e];
        }
        #pragma unroll
        for (int dt = 0; dt < 2; dt++) {
            int d = wid * 64 + dt * 32 + l31;
            #pragma unroll
            for (int r = 0; r < 16; r++) {
                int q = qt2 * 32 + (r & 3) + 8 * (r >> 2) + 4 * lh;
                ao_t[((size_t)bb * S_ + s0 + q) * C_ + d] = f2bf(o_[qt2][dt][r] * rl[r]);
            }
        }
    }
}

extern "C" void kernel_launch(void* const* d_in, const int* in_sizes, int n_in,
                              void* d_out, int out_size, void* d_ws, size_t ws_size,
                              hipStream_t stream) {
    const float* x  = (const float*)d_in[0];
    const float* gg = (const float*)d_in[1];
    const float* gb = (const float*)d_in[2];
    const float* wq = (const float*)d_in[3];
    const float* bq = (const float*)d_in[4];
    const float* wk = (const float*)d_in[5];
    const float* bk = (const float*)d_in[6];
    const float* wv = (const float*)d_in[7];
    const float* bv = (const float*)d_in[8];
    const float* wo = (const float*)d_in[9];
    const float* bo = (const float*)d_in[10];
    float* out = (float*)d_out;

    char* ws = (char*)d_ws;
    const size_t BUF = (size_t)B_ * S_ * C_ * 2;    // 16 MB bf16 buffer
    ushort* h_t  = (ushort*)(ws);
    ushort* q_t  = (ushort*)(ws + BUF);
    ushort* k_t  = (ushort*)(ws + 2 * BUF);
    ushort* v_n  = (ushort*)(ws + 3 * BUF);
    ushort* ao_t = (ushort*)(ws + 4 * BUF);
    ushort* wb   = (ushort*)(ws + 5 * BUF);         // 4 x 262144 bf16
    float* stats = (float*)(ws + 5 * BUF + 4 * 524288);

    wconv_kernel<<<1024, 256, 0, stream>>>(wq, wk, wv, wo, wb);
    gn_stats_kernel<<<128, 512, 0, stream>>>(x, stats);
    gn_apply_kernel<<<dim3(16, 32, B_), 256, 0, stream>>>(x, gg, gb, stats, h_t);

    dim3 ggrid(32, 8, B_);
    gemm_kernel<0><<<ggrid, 256, 0, stream>>>(wb,          h_t, bq, (void*)q_t, nullptr, SCALE_);
    gemm_kernel<0><<<ggrid, 256, 0, stream>>>(wb + 262144, h_t, bk, (void*)k_t, nullptr, 1.0f);
    gemm_kernel<1><<<ggrid, 256, 0, stream>>>(wb + 524288, h_t, bv, (void*)v_n, nullptr, 1.0f);

    attn_kernel<<<dim3(64, B_), 512, 159488, stream>>>(q_t, k_t, v_n, ao_t);

    gemm_kernel<2><<<ggrid, 256, 0, stream>>>(wb + 786432, ao_t, bo, (void*)out, x, 1.0f);
}

// Round 6
// 450.206 us; speedup vs baseline: 1.4169x; 1.0382x over previous
//
#include <hip/hip_runtime.h>
#include <cstdint>
#include <cstddef>

typedef __attribute__((ext_vector_type(8))) short short8;      // bf16x8 MFMA fragment
typedef __attribute__((ext_vector_type(8))) _Float16 half8;    // f16x8 LDS tile
typedef __attribute__((ext_vector_type(4))) float f32x4;       // fp32x4
typedef __attribute__((ext_vector_type(16))) float f32x16;     // fp32x16 accumulator (32x32)

#define C_ 512
#define S_ 4096
#define B_ 4
#define EPS_ 1e-6f
#define SCALE_ 0.04419417382415922f   // 512^-0.5, folded into q

__device__ __forceinline__ ushort f2bf(float f) {
    union { float f; uint32_t u; } v; v.f = f;
    uint32_t r = v.u + 0x7FFFu + ((v.u >> 16) & 1u);
    return (ushort)(r >> 16);
}

// ---------------- weight fp32 -> bf16 ----------------
__global__ void wconv_kernel(const float* __restrict__ wq, const float* __restrict__ wk,
                             const float* __restrict__ wv, const float* __restrict__ wo,
                             ushort* __restrict__ out) {
    int i = blockIdx.x * 256 + threadIdx.x;   // grid covers exactly 262144
    out[i]          = f2bf(wq[i]);
    out[262144 + i] = f2bf(wk[i]);
    out[524288 + i] = f2bf(wv[i]);
    out[786432 + i] = f2bf(wo[i]);
}

// ---------------- GroupNorm stats: one block per (b,g) ----------------
__global__ __launch_bounds__(512) void gn_stats_kernel(const float* __restrict__ x,
                                                       float* __restrict__ stats) {
    int bg = blockIdx.x;                       // b*32+g ; channels contiguous
    const float* xp = x + (size_t)bg * 16 * S_;
    float sum = 0.f, ss = 0.f;
    for (int i = threadIdx.x; i < 16 * S_; i += 512) {
        float v = xp[i];
        sum += v; ss += v * v;
    }
    #pragma unroll
    for (int off = 32; off; off >>= 1) {
        sum += __shfl_down(sum, off);
        ss  += __shfl_down(ss, off);
    }
    __shared__ float r0[8], r1[8];
    int wid = threadIdx.x >> 6;
    if ((threadIdx.x & 63) == 0) { r0[wid] = sum; r1[wid] = ss; }
    __syncthreads();
    if (threadIdx.x == 0) {
        float ts = 0.f, tq = 0.f;
        #pragma unroll
        for (int w = 0; w < 8; w++) { ts += r0[w]; tq += r1[w]; }
        float mean = ts / 65536.f;
        float var  = tq / 65536.f - mean * mean;
        stats[bg * 2]     = mean;
        stats[bg * 2 + 1] = rsqrtf(var + EPS_);
    }
}

// ---------------- GroupNorm apply + transpose to h_t[s][c] bf16 ----------------
__global__ __launch_bounds__(256) void gn_apply_kernel(const float* __restrict__ x,
        const float* __restrict__ gamma, const float* __restrict__ beta,
        const float* __restrict__ stats, ushort* __restrict__ h_t) {
    int sc = blockIdx.x, g = blockIdx.y, b = blockIdx.z;
    int c0 = g * 16;
    int bg = b * 32 + g;
    float mean = stats[bg * 2], rstd = stats[bg * 2 + 1];
    int t = threadIdx.x;
    __shared__ float tile[16][257];
    const float* xp = x + ((size_t)b * C_ + c0) * S_ + sc * 256;
    {
        int c = t >> 4, s0 = (t & 15) * 4;
        const float* src = xp + (size_t)c * S_;
        #pragma unroll
        for (int j = 0; j < 4; j++) {
            float4 d = *(const float4*)(src + s0 + 64 * j);
            tile[c][s0 + 64 * j + 0] = d.x;
            tile[c][s0 + 64 * j + 1] = d.y;
            tile[c][s0 + 64 * j + 2] = d.z;
            tile[c][s0 + 64 * j + 3] = d.w;
        }
    }
    __syncthreads();
    {
        float vv[16];
        #pragma unroll
        for (int ci = 0; ci < 16; ci++) {
            float a = rstd * gamma[c0 + ci];
            float bb2 = beta[c0 + ci] - mean * a;
            vv[ci] = tile[ci][t] * a + bb2;
        }
        uint4 lo, hi;
        lo.x = (uint32_t)f2bf(vv[0])  | ((uint32_t)f2bf(vv[1])  << 16);
        lo.y = (uint32_t)f2bf(vv[2])  | ((uint32_t)f2bf(vv[3])  << 16);
        lo.z = (uint32_t)f2bf(vv[4])  | ((uint32_t)f2bf(vv[5])  << 16);
        lo.w = (uint32_t)f2bf(vv[6])  | ((uint32_t)f2bf(vv[7])  << 16);
        hi.x = (uint32_t)f2bf(vv[8])  | ((uint32_t)f2bf(vv[9])  << 16);
        hi.y = (uint32_t)f2bf(vv[10]) | ((uint32_t)f2bf(vv[11]) << 16);
        hi.z = (uint32_t)f2bf(vv[12]) | ((uint32_t)f2bf(vv[13]) << 16);
        hi.w = (uint32_t)f2bf(vv[14]) | ((uint32_t)f2bf(vv[15]) << 16);
        ushort* dst = h_t + ((size_t)b * S_ + sc * 256 + t) * C_ + c0;
        *(uint4*)dst = lo;
        *(uint4*)(dst + 8) = hi;
    }
}

// ---------------- GEMM (m97-style): 128x128 tile, 32x32x16 MFMA, gload_lds dbuf ----
// out[o][s] = sum_c W[o][c] * Bt[s][c] (+bias)
// MODE 0: bf16 out transposed [B][S][C], val=(acc+bias)*scale   (q_t, k_t)
// MODE 1: bf16 out natural    [B][C][S], val=acc+bias           (v)
// MODE 2: f32  out natural    [B][C][S], val=x+acc+bias         (final)
template <int MODE>
__global__ __launch_bounds__(256, 2) void gemm_kernel(
        const ushort* __restrict__ A,     // [512][512] bf16 weights (K contig)
        const ushort* __restrict__ Bt,    // [B][4096][512] bf16 (K contig)
        const float* __restrict__ bias,
        void* __restrict__ outp,
        const float* __restrict__ xres,
        float scale) {
    int bb = blockIdx.z;
    int m0 = blockIdx.y * 128;
    int n0 = blockIdx.x * 128;
    const ushort* Ap = A + (size_t)m0 * 512;
    const ushort* Bp = Bt + (size_t)bb * S_ * C_ + (size_t)n0 * 512;

    extern __shared__ char lds[];

    int t = threadIdx.x, lane = t & 63, wid = t >> 6;
    int l31 = lane & 31, lh = lane >> 5;
    int wm = (wid >> 1) * 64, wn = (wid & 1) * 64;

    f32x16 acc[2][2] = {};

    #define G_STAGE(sbuf, k0)                                                            \
        {                                                                                \
            char* Adst = lds + (sbuf) * 16384;                                           \
            char* Bdst = lds + 32768 + (sbuf) * 16384;                                   \
            _Pragma("unroll")                                                            \
            for (int i_ = 0; i_ < 4; i_++) {                                             \
                int cb = wid * 64 + i_ * 256;                                            \
                int cid = cb + lane;                                                     \
                int row = cid >> 3, c16 = cid & 7;                                       \
                int sw = ((c16 * 16) ^ ((row & 7) << 4));                                \
                const char* sa = (const char*)(Ap + (size_t)row * 512 + (k0)) + sw;      \
                __builtin_amdgcn_global_load_lds(                                        \
                    (const __attribute__((address_space(1))) unsigned int*)sa,           \
                    (__attribute__((address_space(3))) unsigned int*)(Adst + cb * 16),   \
                    16, 0, 0);                                                           \
                const char* sb = (const char*)(Bp + (size_t)row * 512 + (k0)) + sw;      \
                __builtin_amdgcn_global_load_lds(                                        \
                    (const __attribute__((address_space(1))) unsigned int*)sb,           \
                    (__attribute__((address_space(3))) unsigned int*)(Bdst + cb * 16),   \
                    16, 0, 0);                                                           \
            }                                                                            \
        }

    G_STAGE(0, 0);
    asm volatile("s_waitcnt vmcnt(0)" ::: "memory");
    __builtin_amdgcn_s_barrier();
    asm volatile("" ::: "memory");

    for (int k0 = 0; k0 < 512; k0 += 64) {
        int s = (k0 >> 6) & 1;
        if (k0 + 64 < 512) G_STAGE(s ^ 1, k0 + 64);
        char* Al = lds + s * 16384;
        char* Bl = lds + 32768 + s * 16384;
        #pragma unroll
        for (int ks = 0; ks < 4; ks++) {
            short8 af[2], bfr[2];
            #pragma unroll
            for (int i = 0; i < 2; i++) {
                int rowa = wm + i * 32 + l31;
                af[i] = *(const short8*)(Al + rowa * 128 + ((ks * 32 + lh * 16) ^ ((rowa & 7) << 4)));
                int rowb = wn + i * 32 + l31;
                bfr[i] = *(const short8*)(Bl + rowb * 128 + ((ks * 32 + lh * 16) ^ ((rowb & 7) << 4)));
            }
            #pragma unroll
            for (int i = 0; i < 2; i++)
                #pragma unroll
                for (int j = 0; j < 2; j++)
                    acc[i][j] = __builtin_amdgcn_mfma_f32_32x32x16_bf16(af[i], bfr[j], acc[i][j], 0, 0, 0);
        }
        asm volatile("s_waitcnt vmcnt(0) lgkmcnt(0)" ::: "memory");
        __builtin_amdgcn_s_barrier();
        asm volatile("" ::: "memory");
    }
    #undef G_STAGE

    // epilogue: acc[i][j][q*4+r] -> m = m0+wm+i*32+q*8+4*lh+r, n = n0+wn+j*32+l31
    #pragma unroll
    for (int i = 0; i < 2; i++) {
        #pragma unroll
        for (int q = 0; q < 4; q++) {
            int mbase = m0 + wm + i * 32 + q * 8 + 4 * lh;
            float bs[4];
            #pragma unroll
            for (int r = 0; r < 4; r++) bs[r] = bias[mbase + r];
            #pragma unroll
            for (int j = 0; j < 2; j++) {
                int n = n0 + wn + j * 32 + l31;
                if (MODE == 0) {
                    ushort* O = (ushort*)outp + ((size_t)bb * S_ + n) * C_ + mbase;
                    uint2 pp;
                    pp.x = (uint32_t)f2bf((acc[i][j][q * 4 + 0] + bs[0]) * scale) |
                           ((uint32_t)f2bf((acc[i][j][q * 4 + 1] + bs[1]) * scale) << 16);
                    pp.y = (uint32_t)f2bf((acc[i][j][q * 4 + 2] + bs[2]) * scale) |
                           ((uint32_t)f2bf((acc[i][j][q * 4 + 3] + bs[3]) * scale) << 16);
                    *(uint2*)O = pp;
                } else if (MODE == 1) {
                    ushort* O = (ushort*)outp + (size_t)bb * C_ * S_ + (size_t)mbase * S_ + n;
                    #pragma unroll
                    for (int r = 0; r < 4; r++) O[(size_t)r * S_] = f2bf(acc[i][j][q * 4 + r] + bs[r]);
                } else {
                    float* O = (float*)outp + (size_t)bb * C_ * S_ + (size_t)mbase * S_ + n;
                    const float* X = xres + (size_t)bb * C_ * S_ + (size_t)mbase * S_ + n;
                    #pragma unroll
                    for (int r = 0; r < 4; r++)
                        O[(size_t)r * S_] = X[(size_t)r * S_] + acc[i][j][q * 4 + r] + bs[r];
                }
            }
        }
    }
}

// ---------------- Flash attention, pipelined + XCD-clustered + defer-rescale ----
// 1-D grid 256: bb=(id&7)>>1, qb=((id&1)<<5)|(id>>3)  -> each XCD (id%8) hosts 32
// phase-aligned blocks of one (batch, half) => K/V tiles stay L2-resident.
// QBLK=64, KVBLK=64, D=C=512. q_t,k_t: [B][S][C] bf16 (q pre-scaled).
// v: [B][C][S] bf16.  ao_t: [B][S][C] bf16.
//
// LDS map (159552 B):
//   Kb0/Kb1 : 2 x [64 kv][1024B] XOR-swizzled                      0..65536..131072
//   S_lds   : [2 ch][64 q][72] f16 (stride 144B, self-swizzled) 131072..149504
//   P_lds   : [64 q][144B] bf16                                 149504..158720
//   st_m/l/f: [64] f32 each; rflag int                          158720..159492
#define KBUF_SZ  65536
#define SLDS_OFF 131072
#define PLDS_OFF 149504
#define STM_OFF  158720

__device__ __forceinline__ void stage_k(const ushort* kp, int kv0, int wid, int lane, char* Kbuf) {
    #pragma unroll
    for (int p = 0; p < 8; p++) {
        int row = wid * 8 + p;
        // pre-swizzled global source; LDS dest linear (base + lane*16)
        const char* src = (const char*)(kp + (size_t)(kv0 + row) * C_) + ((lane * 16) ^ ((row & 7) << 4));
        __builtin_amdgcn_global_load_lds(
            (const __attribute__((address_space(1))) unsigned int*)src,
            (__attribute__((address_space(3))) unsigned int*)(Kbuf + row * 1024),
            16, 0, 0);
    }
}

__global__ __launch_bounds__(512, 2) void attn_kernel(const ushort* __restrict__ q_t,
        const ushort* __restrict__ k_t, const ushort* __restrict__ v,
        ushort* __restrict__ ao_t) {
    constexpr int NIT = S_ / 64;
    int id = blockIdx.x;
    int bb = (id & 7) >> 1;
    int qb = ((id & 1) << 5) | (id >> 3);
    int s0 = qb * 64;
    const ushort* qp = q_t + (size_t)bb * S_ * C_;
    const ushort* kp = k_t + (size_t)bb * S_ * C_;
    const ushort* vp = v   + (size_t)bb * C_ * S_;

    extern __shared__ char lds[];
    char* Kbuf0 = lds;
    char* Kbuf1 = lds + KBUF_SZ;
    _Float16* S_lds = (_Float16*)(lds + SLDS_OFF);
    char*  P_lds = lds + PLDS_OFF;
    float* st_m  = (float*)(lds + STM_OFF);
    float* st_l  = st_m + 64;
    float* st_f  = st_m + 128;
    int*   rflag = (int*)(st_m + 192);

    int t = threadIdx.x, lane = t & 63, wid = t >> 6;
    int l31 = lane & 31, lh = lane >> 5;
    int qt = (wid >> 2) & 1, nt = (wid >> 1) & 1, ch = wid & 1;

    if (t < 64) { st_m[t] = -1e30f; st_l[t] = 0.f; }
    if (t == 0) *rflag = 0;

    // Q fragments in registers: wave covers rows qt*32..+31, c-half ch (256 c)
    short8 qf[16];
    {
        const ushort* qrow = qp + (size_t)(s0 + qt * 32 + l31) * C_ + ch * 256 + lh * 8;
        #pragma unroll
        for (int ks = 0; ks < 16; ks++)
            qf[ks] = *(const short8*)(qrow + ks * 16);
    }
    f32x16 o_[2][2] = {};

    // hoisted per-iter bases
    const ushort* vdb_base = vp + (size_t)(wid * 64 + l31) * S_ + lh * 8;

    stage_k(kp, 0, wid, lane, Kbuf0);
    asm volatile("s_waitcnt vmcnt(0) lgkmcnt(0)" ::: "memory");
    __builtin_amdgcn_s_barrier();
    asm volatile("" ::: "memory");

    for (int it = 0; it < NIT; it++) {
        int kv0 = it * 64;
        char* Kcur = (it & 1) ? Kbuf1 : Kbuf0;
        char* Knxt = (it & 1) ? Kbuf0 : Kbuf1;

        // ---- V prefetch into regs (consumed in PV this iter) — issue FIRST
        short8 vb[2][4];
        {
            const ushort* vdb = vdb_base + kv0;
            #pragma unroll
            for (int dt = 0; dt < 2; dt++)
                #pragma unroll
                for (int ks2 = 0; ks2 < 4; ks2++)
                    vb[dt][ks2] = *(const short8*)(vdb + (size_t)dt * 32 * S_ + ks2 * 16);
        }
        // ---- async stage of next K tile (drained at barrier C, full-iter cover)
        if (it + 1 < NIT)
            stage_k(kp, kv0 + 64, wid, lane, Knxt);

        // ---- S-phase: wave (qt,nt,ch) computes partial S[qt][nt] over its c-half
        f32x16 sacc = {};
        {
            int krow = nt * 32 + l31;
            const char* kb = Kcur + krow * 1024;
            int sw = (krow & 7) << 4;
            int cb0 = ch * 512 + lh * 16;
            #pragma unroll
            for (int ks = 0; ks < 16; ks++) {
                short8 kf = *(const short8*)(kb + ((cb0 + ks * 32) ^ sw));
                sacc = __builtin_amdgcn_mfma_f32_32x32x16_bf16(qf[ks], kf, sacc, 0, 0, 0);
            }
        }
        {
            _Float16* Sp = S_lds + (size_t)ch * 4608 + (size_t)(qt * 32) * 72 + nt * 32 + l31;
            #pragma unroll
            for (int r = 0; r < 16; r++) {
                int qrow = (r & 3) + 8 * (r >> 2) + 4 * lh;
                Sp[qrow * 72] = (_Float16)sacc[r];
            }
        }
        asm volatile("s_waitcnt lgkmcnt(0)" ::: "memory");
        __builtin_amdgcn_s_barrier();                    // A: S visible
        asm volatile("" ::: "memory");

        // ---- softmax: 8 threads per q-row, thread covers kv j*8..+7
        {
            int row = t >> 3, j = t & 7;
            half8 h0 = *(const half8*)((const char*)S_lds + (size_t)row * 144 + j * 16);
            half8 h1 = *(const half8*)((const char*)S_lds + 9216 + (size_t)row * 144 + j * 16);
            float sv[8];
            #pragma unroll
            for (int i = 0; i < 8; i++) sv[i] = (float)h0[i] + (float)h1[i];
            float mx = sv[0];
            #pragma unroll
            for (int i = 1; i < 8; i++) mx = fmaxf(mx, sv[i]);
            mx = fmaxf(mx, __shfl_xor(mx, 1));
            mx = fmaxf(mx, __shfl_xor(mx, 2));
            mx = fmaxf(mx, __shfl_xor(mx, 4));
            float mold = st_m[row];
            bool need = (mx > mold + 6.0f);          // T13 defer-rescale
            float mnew = need ? mx : mold;
            if (need) *rflag = 1;                    // benign race: all write 1
            float ps = 0.f;
            uint32_t pk[4];
            #pragma unroll
            for (int i = 0; i < 4; i++) {
                float p0 = __expf(sv[2 * i]     - mnew);
                float p1 = __expf(sv[2 * i + 1] - mnew);
                ps += p0 + p1;
                pk[i] = (uint32_t)f2bf(p0) | ((uint32_t)f2bf(p1) << 16);
            }
            *(uint4*)(P_lds + (size_t)row * 144 + j * 16) = *(uint4*)pk;
            ps += __shfl_xor(ps, 1); ps += __shfl_xor(ps, 2); ps += __shfl_xor(ps, 4);
            if (j == 0) {
                float ef = need ? __expf(mold - mnew) : 1.0f;
                if (need) st_m[row] = mnew;
                st_f[row] = ef;
                st_l[row] = st_l[row] * ef + ps;
            }
        }
        asm volatile("s_waitcnt lgkmcnt(0)" ::: "memory");
        __builtin_amdgcn_s_barrier();                    // B: P + st + rflag visible
        asm volatile("" ::: "memory");

        // ---- PV: wave owns d-slice wid*64; A=P from LDS, B=V from prefetched regs
        {
            if (*rflag) {
                #pragma unroll
                for (int qt2 = 0; qt2 < 2; qt2++) {
                    f32x4 f0 = *(const f32x4*)(st_f + qt2 * 32 + 0  + 4 * lh);
                    f32x4 f1 = *(const f32x4*)(st_f + qt2 * 32 + 8  + 4 * lh);
                    f32x4 f2 = *(const f32x4*)(st_f + qt2 * 32 + 16 + 4 * lh);
                    f32x4 f3 = *(const f32x4*)(st_f + qt2 * 32 + 24 + 4 * lh);
                    float fr[16];
                    #pragma unroll
                    for (int e = 0; e < 4; e++) {
                        fr[e] = f0[e]; fr[4 + e] = f1[e]; fr[8 + e] = f2[e]; fr[12 + e] = f3[e];
                    }
                    #pragma unroll
                    for (int dt = 0; dt < 2; dt++)
                        #pragma unroll
                        for (int r = 0; r < 16; r++)
                            o_[qt2][dt][r] *= fr[r];
                }
            }
            short8 pa[2][4];
            #pragma unroll
            for (int qt2 = 0; qt2 < 2; qt2++)
                #pragma unroll
                for (int ks2 = 0; ks2 < 4; ks2++)
                    pa[qt2][ks2] = *(const short8*)(P_lds + (size_t)(qt2 * 32 + l31) * 144 + ks2 * 32 + lh * 16);
            #pragma unroll
            for (int qt2 = 0; qt2 < 2; qt2++)
                #pragma unroll
                for (int dt = 0; dt < 2; dt++)
                    #pragma unroll
                    for (int ks2 = 0; ks2 < 4; ks2++)
                        o_[qt2][dt] = __builtin_amdgcn_mfma_f32_32x32x16_bf16(pa[qt2][ks2], vb[dt][ks2], o_[qt2][dt], 0, 0, 0);
        }
        asm volatile("s_waitcnt vmcnt(0) lgkmcnt(0)" ::: "memory");
        __builtin_amdgcn_s_barrier();                    // C: K stage complete, P reads done
        asm volatile("" ::: "memory");
        if (t == 0) *rflag = 0;    // reset; ordered vs next set by barrier A
    }

    // ---- epilogue: O / l -> bf16 -> ao_t[s][c]
    #pragma unroll
    for (int qt2 = 0; qt2 < 2; qt2++) {
        f32x4 l0 = *(const f32x4*)(st_l + qt2 * 32 + 0  + 4 * lh);
        f32x4 l1 = *(const f32x4*)(st_l + qt2 * 32 + 8  + 4 * lh);
        f32x4 l2 = *(const f32x4*)(st_l + qt2 * 32 + 16 + 4 * lh);
        f32x4 l3 = *(const f32x4*)(st_l + qt2 * 32 + 24 + 4 * lh);
        float rl[16];
        #pragma unroll
        for (int e = 0; e < 4; e++) {
            rl[e] = 1.0f / l0[e]; rl[4 + e] = 1.0f / l1[e];
            rl[8 + e] = 1.0f / l2[e]; rl[12 + e] = 1.0f / l3[e];
        }
        #pragma unroll
        for (int dt = 0; dt < 2; dt++) {
            int d = wid * 64 + dt * 32 + l31;
            #pragma unroll
            for (int r = 0; r < 16; r++) {
                int q = qt2 * 32 + (r & 3) + 8 * (r >> 2) + 4 * lh;
                ao_t[((size_t)bb * S_ + s0 + q) * C_ + d] = f2bf(o_[qt2][dt][r] * rl[r]);
            }
        }
    }
}

extern "C" void kernel_launch(void* const* d_in, const int* in_sizes, int n_in,
                              void* d_out, int out_size, void* d_ws, size_t ws_size,
                              hipStream_t stream) {
    const float* x  = (const float*)d_in[0];
    const float* gg = (const float*)d_in[1];
    const float* gb = (const float*)d_in[2];
    const float* wq = (const float*)d_in[3];
    const float* bq = (const float*)d_in[4];
    const float* wk = (const float*)d_in[5];
    const float* bk = (const float*)d_in[6];
    const float* wv = (const float*)d_in[7];
    const float* bv = (const float*)d_in[8];
    const float* wo = (const float*)d_in[9];
    const float* bo = (const float*)d_in[10];
    float* out = (float*)d_out;

    char* ws = (char*)d_ws;
    const size_t BUF = (size_t)B_ * S_ * C_ * 2;    // 16 MB bf16 buffer
    ushort* h_t  = (ushort*)(ws);
    ushort* q_t  = (ushort*)(ws + BUF);
    ushort* k_t  = (ushort*)(ws + 2 * BUF);
    ushort* v_n  = (ushort*)(ws + 3 * BUF);
    ushort* ao_t = (ushort*)(ws + 4 * BUF);
    ushort* wb   = (ushort*)(ws + 5 * BUF);         // 4 x 262144 bf16
    float* stats = (float*)(ws + 5 * BUF + 4 * 524288);

    wconv_kernel<<<1024, 256, 0, stream>>>(wq, wk, wv, wo, wb);
    gn_stats_kernel<<<128, 512, 0, stream>>>(x, stats);
    gn_apply_kernel<<<dim3(16, 32, B_), 256, 0, stream>>>(x, gg, gb, stats, h_t);

    dim3 ggrid(32, 4, B_);
    gemm_kernel<0><<<ggrid, 256, 65536, stream>>>(wb,          h_t, bq, (void*)q_t, nullptr, SCALE_);
    gemm_kernel<0><<<ggrid, 256, 65536, stream>>>(wb + 262144, h_t, bk, (void*)k_t, nullptr, 1.0f);
    gemm_kernel<1><<<ggrid, 256, 65536, stream>>>(wb + 524288, h_t, bv, (void*)v_n, nullptr, 1.0f);

    attn_kernel<<<256, 512, 159552, stream>>>(q_t, k_t, v_n, ao_t);

    gemm_kernel<2><<<ggrid, 256, 65536, stream>>>(wb + 786432, ao_t, bo, (void*)out, x, 1.0f);
}